// Round 1
// baseline (401.955 us; speedup 1.0000x reference)
//
#include <hip/hip_runtime.h>

// NestedDropout: out[i,j] = X[i,j] if j < clip(geom[i]*8, 8, 512) else 0.
// B = 131072 rows, FEAT_DIM = 512 float32. Memory-bound masked copy.
//
// R1 change vs baseline: 4 rows per wave (unrolled), so each lane has
// 8 independent nontemporal loads + 8 stores in flight (vs 2+2), the four
// wave-uniform geom reads merge into one s_load_dwordx4, and wave/WG count
// drops 4x. Pure MLP/latency experiment; traffic is unchanged.
//  - cutoff loads via readfirstlane -> SGPR chain (scalar cache).
//  - loads past cutoff skipped (~2x less HBM read on average).
//  - nontemporal on streaming X/out (403 MB >> 32 MB L2).

typedef float v4f __attribute__((ext_vector_type(4)));

constexpr int FEAT  = 512;
constexpr int GROUP = 8;
constexpr int VPR   = FEAT / 4;   // float4 vectors per row = 128
constexpr int RPW   = 4;          // rows per wave
constexpr int WPB   = 4;          // waves per block (256 threads)
constexpr int RPB   = RPW * WPB;  // rows per block = 16

__global__ __launch_bounds__(256) void NestedDropout_60430189854823_kernel(
    const v4f* __restrict__ X4,
    const int* __restrict__ geom,
    v4f*       __restrict__ out4,
    int nrows)
{
    int wave = blockIdx.x * WPB + (threadIdx.x >> 6);
    int lane = threadIdx.x & 63;

    // wave-uniform base row -> SGPR; 4 consecutive rows per wave
    int base = __builtin_amdgcn_readfirstlane(wave * RPW);
    if (base >= nrows) return;

    // scalar phase: 4 cutoffs from one merged s_load
    int cvec[RPW];
    #pragma unroll
    for (int i = 0; i < RPW; ++i) {
        int r = base + i;
        int gi = r < nrows ? r : nrows - 1;        // tail-safe (no-op at B=131072)
        int c = geom[gi] * GROUP;
        c = c < GROUP ? GROUP : c;
        c = c > FEAT  ? FEAT  : c;
        cvec[i] = c >> 2;                          // float4s kept (>= 2)
    }

    // issue all 8 predicated loads before any store -> 8-deep MLP per lane
    v4f a[RPW], b[RPW];
    #pragma unroll
    for (int i = 0; i < RPW; ++i) {
        a[i] = (v4f)(0.0f);
        b[i] = (v4f)(0.0f);
        bool ok = (base + i) < nrows;
        const v4f* xrow = X4 + (size_t)(base + i) * VPR;
        if (ok && lane < cvec[i])      a[i] = __builtin_nontemporal_load(&xrow[lane]);
        if (ok && lane + 64 < cvec[i]) b[i] = __builtin_nontemporal_load(&xrow[lane + 64]);
    }

    #pragma unroll
    for (int i = 0; i < RPW; ++i) {
        if ((base + i) >= nrows) break;
        v4f* orow = out4 + (size_t)(base + i) * VPR;
        __builtin_nontemporal_store(a[i], &orow[lane]);
        __builtin_nontemporal_store(b[i], &orow[lane + 64]);
    }
}

extern "C" void kernel_launch(void* const* d_in, const int* in_sizes, int n_in,
                              void* d_out, int out_size, void* d_ws, size_t ws_size,
                              hipStream_t stream) {
    const v4f* X4   = (const v4f*)d_in[0];   // [B, 512] float32
    const int* geom = (const int*)d_in[1];   // [B] int32
    v4f*       out4 = (v4f*)d_out;           // [B, 512] float32

    int nrows = in_sizes[0] / FEAT;          // B = 131072
    int block = 256;                         // 4 waves, 16 rows per block
    int grid  = (nrows + RPB - 1) / RPB;

    NestedDropout_60430189854823_kernel<<<grid, block, 0, stream>>>(
        X4, geom, out4, nrows);
}

// Round 2
// 391.868 us; speedup vs baseline: 1.0257x; 1.0257x over previous
//
#include <hip/hip_runtime.h>

// NestedDropout: out[i,j] = X[i,j] if j < clip(geom[i]*8, 8, 512) else 0.
// B = 131072 rows, FEAT_DIM = 512 float32. Memory-bound masked copy.
//
// R2: revert to R0 baseline. R1 (4 rows/wave, 8-deep MLP) was +10us —
// the kernel is already at its HBM roofline (~60us of the ~392us timed
// window; the other ~336us is two 1.07GB harness poison-fills at ~80%
// of HBM peak, visible as the only top-5 rocprof dispatches).
//
// Structure: one wave64 per row. 128 float4/row = 2 vectors per lane.
//  - cutoff is wave-uniform -> readfirstlane forces an s_load_dword (SMEM)
//    instead of a 64-lane VMEM broadcast, shortening the dependent chain.
//  - two independent predicated loads + two stores per lane -> 2x MLP.
//  - nontemporal on the streaming X/out traffic (each byte touched once,
//    385 MB >> 32 MB L2) to avoid L2 pollution.
//  - loads past cutoff are skipped entirely -> ~2x less HBM read on average.

typedef float v4f __attribute__((ext_vector_type(4)));

constexpr int FEAT  = 512;
constexpr int GROUP = 8;
constexpr int VPR   = FEAT / 4;   // float4 vectors per row = 128

__global__ __launch_bounds__(256) void NestedDropout_60430189854823_kernel(
    const v4f* __restrict__ X4,
    const int* __restrict__ geom,
    v4f*       __restrict__ out4,
    int nrows)
{
    int wave = blockIdx.x * 4 + (threadIdx.x >> 6);   // 4 waves per block
    int lane = threadIdx.x & 63;
    if (wave >= nrows) return;

    int row = __builtin_amdgcn_readfirstlane(wave);   // wave-uniform -> SGPR

    int cutoff = geom[row] * GROUP;                   // s_load_dword
    cutoff = cutoff < GROUP ? GROUP : cutoff;
    cutoff = cutoff > FEAT  ? FEAT  : cutoff;
    int cvec = cutoff >> 2;                           // float4s kept (>= 2)

    const v4f* xrow = X4   + (size_t)row * VPR;
    v4f*       orow = out4 + (size_t)row * VPR;

    v4f a = (v4f)(0.0f);
    v4f b = (v4f)(0.0f);

    // two independent predicated loads -> both in flight simultaneously
    if (lane < cvec)      a = __builtin_nontemporal_load(&xrow[lane]);
    if (lane + 64 < cvec) b = __builtin_nontemporal_load(&xrow[lane + 64]);

    __builtin_nontemporal_store(a, &orow[lane]);
    __builtin_nontemporal_store(b, &orow[lane + 64]);
}

extern "C" void kernel_launch(void* const* d_in, const int* in_sizes, int n_in,
                              void* d_out, int out_size, void* d_ws, size_t ws_size,
                              hipStream_t stream) {
    const v4f* X4   = (const v4f*)d_in[0];   // [B, 512] float32
    const int* geom = (const int*)d_in[1];   // [B] int32
    v4f*       out4 = (v4f*)d_out;           // [B, 512] float32

    int nrows = in_sizes[0] / FEAT;          // B = 131072
    int block = 256;                         // 4 waves = 4 rows/block
    int grid  = (nrows + 3) / 4;

    NestedDropout_60430189854823_kernel<<<grid, block, 0, stream>>>(
        X4, geom, out4, nrows);
}